// Round 4
// baseline (498.923 us; speedup 1.0000x reference)
//
#include <hip/hip_runtime.h>
#include <stdint.h>
#include <math.h>

// ---------------------------------------------------------------------------
// actions = argmax(log_softmax(relu(x@W1+b1)@W2+b2) + gumbel(fold_in(key0,12345)))
// B=131072, IN=512, RED=128, ACT=2. Output int32 [B].
//
// Round 4 (= round-3 with compile fix): zero-LDS / zero-barrier streaming MFMA.
//  - pre-kernel converts W1 -> W1T hi/lo bf16 in d_ws (L2-resident, 256 KB)
//  - main kernel: A (x) streamed fp32->registers->hi/lo bf16 frags, B frags
//    loaded directly from W1T, 4-product hi/lo MFMA (proven absmax 0),
//    cross-lane shuffle reduction, bit-exact threefry/gumbel epilogue.
// ---------------------------------------------------------------------------

#define IN_CHS 512
#define RED_CHS 128
#define BATCH 131072

typedef __attribute__((ext_vector_type(8))) short bf16x8;
typedef __attribute__((ext_vector_type(4))) float f32x4;
typedef __attribute__((ext_vector_type(4))) float vf4;  // clang-native float4

__host__ __device__ inline void tf2x32(uint32_t k0, uint32_t k1,
                                       uint32_t x0, uint32_t x1,
                                       uint32_t* o0, uint32_t* o1) {
  uint32_t ks2 = k0 ^ k1 ^ 0x1BD11BDAu;
  x0 += k0; x1 += k1;
#define TFR(r) { x0 += x1; x1 = (x1 << r) | (x1 >> (32 - r)); x1 ^= x0; }
  TFR(13) TFR(15) TFR(26) TFR(6)
  x0 += k1; x1 += ks2 + 1u;
  TFR(17) TFR(29) TFR(16) TFR(24)
  x0 += ks2; x1 += k0 + 2u;
  TFR(13) TFR(15) TFR(26) TFR(6)
  x0 += k0; x1 += k1 + 3u;
  TFR(17) TFR(29) TFR(16) TFR(24)
  x0 += k1; x1 += ks2 + 4u;
  TFR(13) TFR(15) TFR(26) TFR(6)
  x0 += ks2; x1 += k0 + 5u;
#undef TFR
  *o0 = x0; *o1 = x1;
}

__device__ __forceinline__ float gumbel_from_bits(uint32_t bits) {
  uint32_t fb = (bits >> 9) | 0x3f800000u;
  float u = __uint_as_float(fb) - 1.0f;
  if (u == 0.0f) u = 1.175494350822287508e-38f;  // FLT_MIN
  float t = -(float)log((double)u);
  return -(float)log((double)t);
}

__device__ __forceinline__ unsigned short f2bf(float f) {
  uint32_t u = __float_as_uint(f);
  return (unsigned short)((u + 0x7fffu + ((u >> 16) & 1u)) >> 16);  // RNE
}
__device__ __forceinline__ float bf2f(unsigned short h) {
  return __uint_as_float(((uint32_t)h) << 16);
}

// ---- pre-kernel: W1[k][c] f32 -> W1T hi/lo bf16 [c][k] -------------------
__global__ __launch_bounds__(256) void w1_convert(
    const float* __restrict__ W1, unsigned short* __restrict__ Bh,
    unsigned short* __restrict__ Bl) {
  const int id = blockIdx.x * 256 + threadIdx.x;  // 8192 threads
  const int c = id >> 6;        // 0..127
  const int k0 = (id & 63) * 8; // 0..504
  bf16x8 hv, lv;
#pragma unroll
  for (int j = 0; j < 8; ++j) {
    float f = W1[(size_t)(k0 + j) * RED_CHS + c];
    unsigned short h = f2bf(f);
    hv[j] = (short)h;
    lv[j] = (short)f2bf(f - bf2f(h));
  }
  *(bf16x8*)(Bh + (size_t)c * IN_CHS + k0) = hv;
  *(bf16x8*)(Bl + (size_t)c * IN_CHS + k0) = lv;
}

// ---- main kernel ----------------------------------------------------------
__global__ __launch_bounds__(256, 3) void rl_head(
    const float* __restrict__ x, const unsigned short* __restrict__ Bhg,
    const unsigned short* __restrict__ Blg, const float* __restrict__ b1,
    const float* __restrict__ W2, const float* __restrict__ b2,
    int* __restrict__ out, uint32_t fk0, uint32_t fk1) {
  const int lane = threadIdx.x & 63;
  const int w = threadIdx.x >> 6;
  const int ln = lane & 15;
  const int quad = lane >> 4;
  const int row0 = blockIdx.x * 128 + w * 32;  // this wave's 32 rows

  // A pointers in fragment pattern: lane (ln,quad) -> row0+ln, k = quad*8
  const float* xp0 = x + (size_t)(row0 + ln) * IN_CHS + quad * 8;
  const float* xp1 = xp0 + (size_t)16 * IN_CHS;

  f32x4 acc[2][8];
#pragma unroll
  for (int i = 0; i < 2; ++i)
#pragma unroll
    for (int j = 0; j < 8; ++j) acc[i][j] = (f32x4)(0.0f);

  // current A raw (8 floats per m-tile)
  vf4 c0a = __builtin_nontemporal_load((const vf4*)(xp0));
  vf4 c0b = __builtin_nontemporal_load((const vf4*)(xp0 + 4));
  vf4 c1a = __builtin_nontemporal_load((const vf4*)(xp1));
  vf4 c1b = __builtin_nontemporal_load((const vf4*)(xp1 + 4));

#pragma unroll 2
  for (int kb = 0; kb < IN_CHS; kb += 32) {
    // software prefetch of next k-step's A
    vf4 n0a = {}, n0b = {}, n1a = {}, n1b = {};
    if (kb + 32 < IN_CHS) {
      n0a = __builtin_nontemporal_load((const vf4*)(xp0 + kb + 32));
      n0b = __builtin_nontemporal_load((const vf4*)(xp0 + kb + 36));
      n1a = __builtin_nontemporal_load((const vf4*)(xp1 + kb + 32));
      n1b = __builtin_nontemporal_load((const vf4*)(xp1 + kb + 36));
    }
    // convert current A -> hi/lo fragments
    bf16x8 ah0, al0, ah1, al1;
    {
      float f[8] = {c0a.x, c0a.y, c0a.z, c0a.w, c0b.x, c0b.y, c0b.z, c0b.w};
      float g[8] = {c1a.x, c1a.y, c1a.z, c1a.w, c1b.x, c1b.y, c1b.z, c1b.w};
#pragma unroll
      for (int j = 0; j < 8; ++j) {
        unsigned short h = f2bf(f[j]);
        ah0[j] = (short)h;
        al0[j] = (short)f2bf(f[j] - bf2f(h));
        unsigned short h2 = f2bf(g[j]);
        ah1[j] = (short)h2;
        al1[j] = (short)f2bf(g[j] - bf2f(h2));
      }
    }
    // B frags straight from L1/L2-resident W1T; 8 col-tiles
#pragma unroll
    for (int ct = 0; ct < 8; ++ct) {
      const size_t boff = (size_t)(ct * 16 + ln) * IN_CHS + kb + quad * 8;
      bf16x8 bh = *(const bf16x8*)(Bhg + boff);
      bf16x8 bl = *(const bf16x8*)(Blg + boff);
      acc[0][ct] = __builtin_amdgcn_mfma_f32_16x16x32_bf16(ah0, bh, acc[0][ct], 0, 0, 0);
      acc[0][ct] = __builtin_amdgcn_mfma_f32_16x16x32_bf16(ah0, bl, acc[0][ct], 0, 0, 0);
      acc[0][ct] = __builtin_amdgcn_mfma_f32_16x16x32_bf16(al0, bh, acc[0][ct], 0, 0, 0);
      acc[0][ct] = __builtin_amdgcn_mfma_f32_16x16x32_bf16(al0, bl, acc[0][ct], 0, 0, 0);
      acc[1][ct] = __builtin_amdgcn_mfma_f32_16x16x32_bf16(ah1, bh, acc[1][ct], 0, 0, 0);
      acc[1][ct] = __builtin_amdgcn_mfma_f32_16x16x32_bf16(ah1, bl, acc[1][ct], 0, 0, 0);
      acc[1][ct] = __builtin_amdgcn_mfma_f32_16x16x32_bf16(al1, bh, acc[1][ct], 0, 0, 0);
      acc[1][ct] = __builtin_amdgcn_mfma_f32_16x16x32_bf16(al1, bl, acc[1][ct], 0, 0, 0);
    }
    c0a = n0a; c0b = n0b; c1a = n1a; c1b = n1b;
  }

  // ---- epilogue: bias+relu -> layer-2 partials -> shuffle reduction ----
  // C layout: col = ct*16 + ln, row = w*32 + rt*16 + quad*4 + reg
  float p[8][2];
#pragma unroll
  for (int s = 0; s < 8; ++s) { p[s][0] = 0.0f; p[s][1] = 0.0f; }
#pragma unroll
  for (int ct = 0; ct < 8; ++ct) {
    const int col = ct * 16 + ln;
    const float bb = b1[col];
    const float w20 = W2[col * 2 + 0];
    const float w21 = W2[col * 2 + 1];
#pragma unroll
    for (int rt = 0; rt < 2; ++rt)
#pragma unroll
      for (int reg = 0; reg < 4; ++reg) {
        float h = acc[rt][ct][reg] + bb;
        h = h > 0.0f ? h : 0.0f;
        p[rt * 4 + reg][0] = fmaf(h, w20, p[rt * 4 + reg][0]);
        p[rt * 4 + reg][1] = fmaf(h, w21, p[rt * 4 + reg][1]);
      }
  }
  // butterfly over the 16 lanes sharing a quad (xor bits 0..3 of lane id)
#pragma unroll
  for (int s = 0; s < 8; ++s)
#pragma unroll
    for (int a = 0; a < 2; ++a) {
      float v = p[s][a];
      v += __shfl_xor(v, 1);
      v += __shfl_xor(v, 2);
      v += __shfl_xor(v, 4);
      v += __shfl_xor(v, 8);
      p[s][a] = v;
    }

  if (ln < 8) {
    float l0 = 0.0f, l1 = 0.0f;
#pragma unroll
    for (int s = 0; s < 8; ++s)
      if (ln == s) { l0 = p[s][0]; l1 = p[s][1]; }
    l0 += b2[0];
    l1 += b2[1];
    const int row = row0 + (ln >> 2) * 16 + quad * 4 + (ln & 3);
    float m = fmaxf(l0, l1);
    float s0 = l0 - m, s1 = l1 - m;
    float e0 = (float)exp((double)s0);
    float e1 = (float)exp((double)s1);
    float lse = (float)log((double)(e0 + e1));
    float lp0 = s0 - lse, lp1 = s1 - lse;
    uint32_t a0, a1, g0b, g1b;
    tf2x32(fk0, fk1, 0u, (uint32_t)(2 * row), &a0, &a1);
    tf2x32(fk0, fk1, 0u, (uint32_t)(2 * row + 1), &g0b, &g1b);
    float g0 = gumbel_from_bits(a0 ^ a1);
    float g1 = gumbel_from_bits(g0b ^ g1b);
    out[row] = ((lp1 + g1) > (lp0 + g0)) ? 1 : 0;
  }
}

extern "C" void kernel_launch(void* const* d_in, const int* in_sizes, int n_in,
                              void* d_out, int out_size, void* d_ws,
                              size_t ws_size, hipStream_t stream) {
  (void)in_sizes; (void)n_in; (void)ws_size; (void)out_size;
  const float* x = (const float*)d_in[0];
  const float* W1 = (const float*)d_in[1];
  const float* b1 = (const float*)d_in[2];
  const float* W2 = (const float*)d_in[3];
  const float* b2 = (const float*)d_in[4];
  int* out = (int*)d_out;

  unsigned short* Bh = (unsigned short*)d_ws;                 // 128x512 bf16
  unsigned short* Bl = Bh + (size_t)RED_CHS * IN_CHS;         // 128x512 bf16

  uint32_t fk0, fk1;
  tf2x32(0u, 0u, 0u, 12345u, &fk0, &fk1);

  w1_convert<<<dim3(32), 256, 0, stream>>>(W1, Bh, Bl);
  rl_head<<<dim3(BATCH / 128), 256, 0, stream>>>(x, Bh, Bl, b1, W2, b2, out,
                                                 fk0, fk1);
}

// Round 5
// 382.551 us; speedup vs baseline: 1.3042x; 1.3042x over previous
//
#include <hip/hip_runtime.h>
#include <stdint.h>
#include <math.h>

// ---------------------------------------------------------------------------
// actions = argmax(log_softmax(relu(x@W1+b1)@W2+b2) + gumbel(fold_in(key0,12345)))
// B=131072, IN=512, RED=128, ACT=2. Output int32 [B].
//
// Round 5: coalesced LDS staging for A (fp32->hi/lo bf16 in regs), B from
// pre-converted W1T via global_load_lds dwordx4 (double-buffered), XOR-swizzled
// LDS layouts (conflict-free b128 frag reads), software-pipelined k-loop.
// 4-product hi/lo MFMA (proven absmax 0); bit-exact threefry/gumbel epilogue.
// ---------------------------------------------------------------------------

#define IN_CHS 512
#define RED_CHS 128
#define BATCH 131072
#define ROWS 256            // rows per block
#define NK 16               // k-steps of 32
#define ABASE_LO 16384      // A lo half offset in LDS
#define BBASE 32768         // B region base in LDS

typedef __attribute__((ext_vector_type(8))) short bf16x8;
typedef __attribute__((ext_vector_type(4))) float f32x4;
typedef __attribute__((ext_vector_type(4))) float vf4;

__host__ __device__ inline void tf2x32(uint32_t k0, uint32_t k1,
                                       uint32_t x0, uint32_t x1,
                                       uint32_t* o0, uint32_t* o1) {
  uint32_t ks2 = k0 ^ k1 ^ 0x1BD11BDAu;
  x0 += k0; x1 += k1;
#define TFR(r) { x0 += x1; x1 = (x1 << r) | (x1 >> (32 - r)); x1 ^= x0; }
  TFR(13) TFR(15) TFR(26) TFR(6)
  x0 += k1; x1 += ks2 + 1u;
  TFR(17) TFR(29) TFR(16) TFR(24)
  x0 += ks2; x1 += k0 + 2u;
  TFR(13) TFR(15) TFR(26) TFR(6)
  x0 += k0; x1 += k1 + 3u;
  TFR(17) TFR(29) TFR(16) TFR(24)
  x0 += k1; x1 += ks2 + 4u;
  TFR(13) TFR(15) TFR(26) TFR(6)
  x0 += ks2; x1 += k0 + 5u;
#undef TFR
  *o0 = x0; *o1 = x1;
}

__device__ __forceinline__ float gumbel_from_bits(uint32_t bits) {
  uint32_t fb = (bits >> 9) | 0x3f800000u;
  float u = __uint_as_float(fb) - 1.0f;
  if (u == 0.0f) u = 1.175494350822287508e-38f;  // FLT_MIN
  float t = -(float)log((double)u);
  return -(float)log((double)t);
}

__device__ __forceinline__ unsigned short f2bf(float f) {
  uint32_t u = __float_as_uint(f);
  return (unsigned short)((u + 0x7fffu + ((u >> 16) & 1u)) >> 16);  // RNE
}
__device__ __forceinline__ float bf2f(unsigned short h) {
  return __uint_as_float(((uint32_t)h) << 16);
}

__device__ __forceinline__ void load_lds_16(const void* gp, void* lp) {
  __builtin_amdgcn_global_load_lds(
      (const __attribute__((address_space(1))) unsigned int*)gp,
      (__attribute__((address_space(3))) unsigned int*)lp, 16, 0, 0);
}

// ---- pre-kernel: W1[k][c] f32 -> W1T hi/lo bf16 [c][k] --------------------
__global__ __launch_bounds__(256) void w1_convert(
    const float* __restrict__ W1, unsigned short* __restrict__ Bh,
    unsigned short* __restrict__ Bl) {
  const int id = blockIdx.x * 256 + threadIdx.x;  // 8192 threads
  const int c = id >> 6;
  const int k0 = (id & 63) * 8;
  bf16x8 hv, lv;
#pragma unroll
  for (int j = 0; j < 8; ++j) {
    float f = W1[(size_t)(k0 + j) * RED_CHS + c];
    unsigned short h = f2bf(f);
    hv[j] = (short)h;
    lv[j] = (short)f2bf(f - bf2f(h));
  }
  *(bf16x8*)(Bh + (size_t)c * IN_CHS + k0) = hv;
  *(bf16x8*)(Bl + (size_t)c * IN_CHS + k0) = lv;
}

// ---- main kernel ----------------------------------------------------------
__global__ __launch_bounds__(256, 2) void rl_head(
    const float* __restrict__ x, const unsigned short* __restrict__ Bhg,
    const unsigned short* __restrict__ Blg, const float* __restrict__ b1,
    const float* __restrict__ W2, const float* __restrict__ b2,
    int* __restrict__ out, uint32_t fk0, uint32_t fk1) {
  // LDS: Ah 16K | Al 16K | B buf0 (hi 8K, lo 8K) | B buf1 (hi 8K, lo 8K)
  // Octet (r,q) of A stored at (r>>4)*1024 + (r&15)*64 + ((q^((r>>1)&3))*16).
  // Same swizzle for B with c in place of r. -> b128 frag reads: each 8-lane
  // phase covers all 8 bank-quads exactly once (conflict-free).
  __shared__ __align__(16) unsigned char smem[65536];

  const int tid = threadIdx.x;
  const int lane = tid & 63;
  const int w = tid >> 6;        // wave id: rows [w*64, w*64+64)
  const int ln = lane & 15;
  const int quad = lane >> 4;
  const int row0 = blockIdx.x * ROWS;

  // fragment-read byte offset (within a 1KB group), shared by A and B
  const int afr = ln * 64 + ((quad ^ ((ln >> 1) & 3)) * 16);

  // ---- A staging constants: thread covers rows p*64+(tid>>2), octet tid&3
  const int swzA = (tid & 3) ^ ((tid >> 3) & 3);
  const int aw = (tid >> 6) * 1024 + ((tid >> 2) & 15) * 64 + swzA * 16;
  const float* xbase = x + (size_t)(row0 + (tid >> 2)) * IN_CHS + (tid & 3) * 8;

  // ---- B loader constants: wave-instr j = w*4+i; lane -> (c, q)
  const unsigned short* gB[4];
  int ldsOffB[4];
#pragma unroll
  for (int i = 0; i < 4; ++i) {
    const int j = w * 4 + i;
    const int g = (j < 8) ? j : j - 8;
    const int c = g * 16 + (lane >> 2);
    const int q = (lane & 3) ^ ((lane >> 3) & 3);
    gB[i] = ((j < 8) ? Bhg : Blg) + (size_t)c * IN_CHS + q * 8;
    ldsOffB[i] = (j < 8) ? j * 1024 : 8192 + (j - 8) * 1024;
  }

  f32x4 acc[4][8];
#pragma unroll
  for (int mt = 0; mt < 4; ++mt)
#pragma unroll
    for (int ct = 0; ct < 8; ++ct) acc[mt][ct] = (f32x4)(0.0f);

  vf4 ar[8];

  // ---- prologue: B(0), B(1) -> LDS; A(0) -> regs -> convert -> LDS
#pragma unroll
  for (int i = 0; i < 4; ++i)
    load_lds_16(gB[i], smem + BBASE + ldsOffB[i]);
#pragma unroll
  for (int i = 0; i < 4; ++i)
    load_lds_16(gB[i] + 32, smem + BBASE + 16384 + ldsOffB[i]);
#pragma unroll
  for (int p = 0; p < 4; ++p) {
    ar[2 * p] = *(const vf4*)(xbase + p * 64 * IN_CHS);
    ar[2 * p + 1] = *(const vf4*)(xbase + p * 64 * IN_CHS + 4);
  }
#pragma unroll
  for (int p = 0; p < 4; ++p) {
    float f[8] = {ar[2 * p].x, ar[2 * p].y, ar[2 * p].z, ar[2 * p].w,
                  ar[2 * p + 1].x, ar[2 * p + 1].y, ar[2 * p + 1].z, ar[2 * p + 1].w};
    bf16x8 hv, lv;
#pragma unroll
    for (int jj = 0; jj < 8; ++jj) {
      unsigned short h = f2bf(f[jj]);
      hv[jj] = (short)h;
      lv[jj] = (short)f2bf(f[jj] - bf2f(h));
    }
    *(bf16x8*)(smem + p * 4096 + aw) = hv;
    *(bf16x8*)(smem + ABASE_LO + p * 4096 + aw) = lv;
  }
  __syncthreads();

  // ---- main k-loop ----
#pragma unroll 2
  for (int k = 0; k < NK; ++k) {
    // issue A(k+1) raw loads (drained at post-MFMA barrier)
    if (k + 1 < NK) {
      const float* xc = xbase + (k + 1) * 32;
#pragma unroll
      for (int p = 0; p < 4; ++p) {
        ar[2 * p] = *(const vf4*)(xc + p * 64 * IN_CHS);
        ar[2 * p + 1] = *(const vf4*)(xc + p * 64 * IN_CHS + 4);
      }
    }
    // MFMA on A(k), B(k)
    {
      const unsigned char* Bb = smem + BBASE + (k & 1) * 16384;
      bf16x8 ah[4], al[4];
#pragma unroll
      for (int mt = 0; mt < 4; ++mt) {
        ah[mt] = *(const bf16x8*)(smem + (w * 4 + mt) * 1024 + afr);
        al[mt] = *(const bf16x8*)(smem + ABASE_LO + (w * 4 + mt) * 1024 + afr);
      }
#pragma unroll
      for (int ct = 0; ct < 8; ++ct) {
        bf16x8 bh = *(const bf16x8*)(Bb + ct * 1024 + afr);
        bf16x8 bl = *(const bf16x8*)(Bb + 8192 + ct * 1024 + afr);
#pragma unroll
        for (int mt = 0; mt < 4; ++mt) {
          acc[mt][ct] = __builtin_amdgcn_mfma_f32_16x16x32_bf16(ah[mt], bh, acc[mt][ct], 0, 0, 0);
          acc[mt][ct] = __builtin_amdgcn_mfma_f32_16x16x32_bf16(ah[mt], bl, acc[mt][ct], 0, 0, 0);
          acc[mt][ct] = __builtin_amdgcn_mfma_f32_16x16x32_bf16(al[mt], bh, acc[mt][ct], 0, 0, 0);
          acc[mt][ct] = __builtin_amdgcn_mfma_f32_16x16x32_bf16(al[mt], bl, acc[mt][ct], 0, 0, 0);
        }
      }
    }
    if (k == NK - 1) break;
    __syncthreads();  // A(k)/B(k) reads done; drains A(k+1) regs (covered by MFMA)
    // B(k+2) into the buffer B(k) just vacated
    if (k + 2 < NK) {
      const int kb2 = (k + 2) * 32;
      unsigned char* Bt = smem + BBASE + (k & 1) * 16384;
#pragma unroll
      for (int i = 0; i < 4; ++i)
        load_lds_16(gB[i] + kb2, Bt + ldsOffB[i]);
    }
    // convert + write A(k+1)
#pragma unroll
    for (int p = 0; p < 4; ++p) {
      float f[8] = {ar[2 * p].x, ar[2 * p].y, ar[2 * p].z, ar[2 * p].w,
                    ar[2 * p + 1].x, ar[2 * p + 1].y, ar[2 * p + 1].z, ar[2 * p + 1].w};
      bf16x8 hv, lv;
#pragma unroll
      for (int jj = 0; jj < 8; ++jj) {
        unsigned short h = f2bf(f[jj]);
        hv[jj] = (short)h;
        lv[jj] = (short)f2bf(f[jj] - bf2f(h));
      }
      *(bf16x8*)(smem + p * 4096 + aw) = hv;
      *(bf16x8*)(smem + ABASE_LO + p * 4096 + aw) = lv;
    }
    __syncthreads();  // A(k+1) visible; B(k+1) was drained at previous barrier
  }

  // ---- epilogue: bias+relu -> layer-2 partials -> shuffle reduction ----
  // C layout: col = ct*16 + ln, row = w*64 + mt*16 + quad*4 + reg
  float p[16][2];
#pragma unroll
  for (int s = 0; s < 16; ++s) { p[s][0] = 0.0f; p[s][1] = 0.0f; }
#pragma unroll
  for (int ct = 0; ct < 8; ++ct) {
    const int col = ct * 16 + ln;
    const float bb = b1[col];
    const float w20 = W2[col * 2 + 0];
    const float w21 = W2[col * 2 + 1];
#pragma unroll
    for (int mt = 0; mt < 4; ++mt)
#pragma unroll
      for (int reg = 0; reg < 4; ++reg) {
        float h = acc[mt][ct][reg] + bb;
        h = h > 0.0f ? h : 0.0f;
        p[mt * 4 + reg][0] = fmaf(h, w20, p[mt * 4 + reg][0]);
        p[mt * 4 + reg][1] = fmaf(h, w21, p[mt * 4 + reg][1]);
      }
  }
#pragma unroll
  for (int s = 0; s < 16; ++s)
#pragma unroll
    for (int a = 0; a < 2; ++a) {
      float v = p[s][a];
      v += __shfl_xor(v, 1);
      v += __shfl_xor(v, 2);
      v += __shfl_xor(v, 4);
      v += __shfl_xor(v, 8);
      p[s][a] = v;
    }

  // lane ln takes slot s=ln: row = row0 + w*64 + (ln>>2)*16 + quad*4 + (ln&3)
  float l0 = 0.0f, l1 = 0.0f;
#pragma unroll
  for (int s = 0; s < 16; ++s)
    if (ln == s) { l0 = p[s][0]; l1 = p[s][1]; }
  l0 += b2[0];
  l1 += b2[1];
  const int row = row0 + w * 64 + (ln >> 2) * 16 + quad * 4 + (ln & 3);
  float m = fmaxf(l0, l1);
  float s0 = l0 - m, s1 = l1 - m;
  float e0 = (float)exp((double)s0);
  float e1 = (float)exp((double)s1);
  float lse = (float)log((double)(e0 + e1));
  float lp0 = s0 - lse, lp1 = s1 - lse;
  uint32_t a0, a1, g0b, g1b;
  tf2x32(fk0, fk1, 0u, (uint32_t)(2 * row), &a0, &a1);
  tf2x32(fk0, fk1, 0u, (uint32_t)(2 * row + 1), &g0b, &g1b);
  float g0 = gumbel_from_bits(a0 ^ a1);
  float g1 = gumbel_from_bits(g0b ^ g1b);
  out[row] = ((lp1 + g1) > (lp0 + g0)) ? 1 : 0;
}

extern "C" void kernel_launch(void* const* d_in, const int* in_sizes, int n_in,
                              void* d_out, int out_size, void* d_ws,
                              size_t ws_size, hipStream_t stream) {
  (void)in_sizes; (void)n_in; (void)ws_size; (void)out_size;
  const float* x = (const float*)d_in[0];
  const float* W1 = (const float*)d_in[1];
  const float* b1 = (const float*)d_in[2];
  const float* W2 = (const float*)d_in[3];
  const float* b2 = (const float*)d_in[4];
  int* out = (int*)d_out;

  unsigned short* Bh = (unsigned short*)d_ws;
  unsigned short* Bl = Bh + (size_t)RED_CHS * IN_CHS;

  uint32_t fk0, fk1;
  tf2x32(0u, 0u, 0u, 12345u, &fk0, &fk1);

  w1_convert<<<dim3(32), 256, 0, stream>>>(W1, Bh, Bl);
  rl_head<<<dim3(BATCH / ROWS), 256, 0, stream>>>(x, Bh, Bl, b1, W2, b2, out,
                                                  fk0, fk1);
}

// Round 6
// 376.896 us; speedup vs baseline: 1.3238x; 1.0150x over previous
//
#include <hip/hip_runtime.h>
#include <stdint.h>
#include <math.h>

// ---------------------------------------------------------------------------
// actions = argmax(log_softmax(relu(x@W1+b1)@W2+b2) + gumbel(fold_in(key0,12345)))
// B=131072, IN=512, RED=128, ACT=2. Output int32 [B].
//
// Round 6: A (x) loaded straight into each wave's registers in MFMA fragment
// layout (no LDS round-trip, no cross-wave A sharing), converted fp32->hi/lo
// bf16 in regs. LDS holds only B (pre-converted W1T hi/lo), double-buffered
// via global_load_lds dwordx4, XOR-swizzled (conflict-free b128 reads).
// ONE barrier per k-step. 128 rows/block -> acc 64 VGPRs -> 3 blocks/CU.
// 4-product hi/lo MFMA (proven absmax 0); bit-exact threefry/gumbel epilogue.
// ---------------------------------------------------------------------------

#define IN_CHS 512
#define RED_CHS 128
#define BATCH 131072
#define ROWS 128
#define NK 16               // k-steps of 32

typedef __attribute__((ext_vector_type(8))) short bf16x8;
typedef __attribute__((ext_vector_type(4))) float f32x4;
typedef __attribute__((ext_vector_type(4))) float vf4;

__host__ __device__ inline void tf2x32(uint32_t k0, uint32_t k1,
                                       uint32_t x0, uint32_t x1,
                                       uint32_t* o0, uint32_t* o1) {
  uint32_t ks2 = k0 ^ k1 ^ 0x1BD11BDAu;
  x0 += k0; x1 += k1;
#define TFR(r) { x0 += x1; x1 = (x1 << r) | (x1 >> (32 - r)); x1 ^= x0; }
  TFR(13) TFR(15) TFR(26) TFR(6)
  x0 += k1; x1 += ks2 + 1u;
  TFR(17) TFR(29) TFR(16) TFR(24)
  x0 += ks2; x1 += k0 + 2u;
  TFR(13) TFR(15) TFR(26) TFR(6)
  x0 += k0; x1 += k1 + 3u;
  TFR(17) TFR(29) TFR(16) TFR(24)
  x0 += k1; x1 += ks2 + 4u;
  TFR(13) TFR(15) TFR(26) TFR(6)
  x0 += ks2; x1 += k0 + 5u;
#undef TFR
  *o0 = x0; *o1 = x1;
}

__device__ __forceinline__ float gumbel_from_bits(uint32_t bits) {
  uint32_t fb = (bits >> 9) | 0x3f800000u;
  float u = __uint_as_float(fb) - 1.0f;
  if (u == 0.0f) u = 1.175494350822287508e-38f;  // FLT_MIN
  float t = -(float)log((double)u);
  return -(float)log((double)t);
}

__device__ __forceinline__ unsigned short f2bf(float f) {
  uint32_t u = __float_as_uint(f);
  return (unsigned short)((u + 0x7fffu + ((u >> 16) & 1u)) >> 16);  // RNE
}
__device__ __forceinline__ float bf2f(unsigned short h) {
  return __uint_as_float(((uint32_t)h) << 16);
}

__device__ __forceinline__ void load_lds_16(const void* gp, void* lp) {
  __builtin_amdgcn_global_load_lds(
      (const __attribute__((address_space(1))) unsigned int*)gp,
      (__attribute__((address_space(3))) unsigned int*)lp, 16, 0, 0);
}

// ---- pre-kernel: W1[k][c] f32 -> W1T hi/lo bf16 [c][k] --------------------
__global__ __launch_bounds__(256) void w1_convert(
    const float* __restrict__ W1, unsigned short* __restrict__ Bh,
    unsigned short* __restrict__ Bl) {
  const int id = blockIdx.x * 256 + threadIdx.x;  // 8192 threads
  const int c = id >> 6;
  const int k0 = (id & 63) * 8;
  bf16x8 hv, lv;
#pragma unroll
  for (int j = 0; j < 8; ++j) {
    float f = W1[(size_t)(k0 + j) * RED_CHS + c];
    unsigned short h = f2bf(f);
    hv[j] = (short)h;
    lv[j] = (short)f2bf(f - bf2f(h));
  }
  *(bf16x8*)(Bh + (size_t)c * IN_CHS + k0) = hv;
  *(bf16x8*)(Bl + (size_t)c * IN_CHS + k0) = lv;
}

// convert 8 fp32 (2 vf4) into hi/lo bf16x8 fragments
__device__ __forceinline__ void cvt_frag(const vf4& a, const vf4& b,
                                         bf16x8& hv, bf16x8& lv) {
  float f[8] = {a.x, a.y, a.z, a.w, b.x, b.y, b.z, b.w};
#pragma unroll
  for (int j = 0; j < 8; ++j) {
    unsigned short h = f2bf(f[j]);
    hv[j] = (short)h;
    lv[j] = (short)f2bf(f[j] - bf2f(h));
  }
}

// ---- main kernel ----------------------------------------------------------
__global__ __launch_bounds__(256, 3) void rl_head(
    const float* __restrict__ x, const unsigned short* __restrict__ Bhg,
    const unsigned short* __restrict__ Blg, const float* __restrict__ b1,
    const float* __restrict__ W2, const float* __restrict__ b2,
    int* __restrict__ out, uint32_t fk0, uint32_t fk1) {
  // LDS = B only: buf0 (hi 8K | lo 8K) | buf1 (hi 8K | lo 8K) = 32 KB.
  // 1 KB group = 16 cols x 32 k bf16; octet q of col c at
  // (c&15)*64 + ((q ^ ((c>>1)&3))*16)  -> conflict-free b128 reads.
  __shared__ __align__(16) unsigned char smem[32768];

  const int tid = threadIdx.x;
  const int lane = tid & 63;
  const int w = tid >> 6;        // wave id: rows [w*32, w*32+32)
  const int ln = lane & 15;
  const int quad = lane >> 4;
  const int row0 = blockIdx.x * ROWS;

  // fragment-read byte offset within a 1 KB group
  const int afr = ln * 64 + ((quad ^ ((ln >> 1) & 3)) * 16);

  // ---- B loader: wave w loads groups j = w*4..w*4+3 (j<8 hi, j>=8 lo)
  const unsigned short* gB[4];
  int ldsOffB[4];
#pragma unroll
  for (int i = 0; i < 4; ++i) {
    const int j = w * 4 + i;
    const int g = j & 7;
    const int c = g * 16 + (lane >> 2);
    const int q = (lane & 3) ^ ((lane >> 3) & 3);
    gB[i] = ((j < 8) ? Bhg : Blg) + (size_t)c * IN_CHS + q * 8;
    ldsOffB[i] = j * 1024;  // hi groups 0..8K, lo groups 8K..16K
  }

  // ---- A: this lane's rows, fragment k-slice
  const float* xpA = x + (size_t)(row0 + w * 32 + ln) * IN_CHS + quad * 8;
  const float* xpB = xpA + (size_t)16 * IN_CHS;

  f32x4 acc[2][8];
#pragma unroll
  for (int mt = 0; mt < 2; ++mt)
#pragma unroll
    for (int ct = 0; ct < 8; ++ct) acc[mt][ct] = (f32x4)(0.0f);

  vf4 ar[2][4];          // two in-flight k-step raw A sets
  bf16x8 fah[2], fal[2]; // current k-step fragments

  // ---- prologue: B(0)->buf0, B(1)->buf1; A(0),A(1) regs; frags(0)
#pragma unroll
  for (int i = 0; i < 4; ++i) load_lds_16(gB[i], smem + ldsOffB[i]);
#pragma unroll
  for (int i = 0; i < 4; ++i) load_lds_16(gB[i] + 32, smem + 16384 + ldsOffB[i]);
  ar[0][0] = *(const vf4*)(xpA);
  ar[0][1] = *(const vf4*)(xpA + 4);
  ar[0][2] = *(const vf4*)(xpB);
  ar[0][3] = *(const vf4*)(xpB + 4);
  ar[1][0] = *(const vf4*)(xpA + 32);
  ar[1][1] = *(const vf4*)(xpA + 36);
  ar[1][2] = *(const vf4*)(xpB + 32);
  ar[1][3] = *(const vf4*)(xpB + 36);
  cvt_frag(ar[0][0], ar[0][1], fah[0], fal[0]);
  cvt_frag(ar[0][2], ar[0][3], fah[1], fal[1]);
  __syncthreads();  // B(0)/B(1) complete (vmcnt(0) drain)

#pragma unroll 2
  for (int k = 0; k < NK; ++k) {
    // issue A(k+2) early (into the set vacated by A(k), already fragged)
    if (k < NK - 2) {
      const float* pA = xpA + (k + 2) * 32;
      const float* pB = xpB + (k + 2) * 32;
      ar[k & 1][0] = *(const vf4*)(pA);
      ar[k & 1][1] = *(const vf4*)(pA + 4);
      ar[k & 1][2] = *(const vf4*)(pB);
      ar[k & 1][3] = *(const vf4*)(pB + 4);
    }
    // MFMA(k): frags + B buf[k&1]
    {
      const unsigned char* Bb = smem + (k & 1) * 16384;
#pragma unroll
      for (int ct = 0; ct < 8; ++ct) {
        bf16x8 bh = *(const bf16x8*)(Bb + ct * 1024 + afr);
        bf16x8 bl = *(const bf16x8*)(Bb + 8192 + ct * 1024 + afr);
#pragma unroll
        for (int mt = 0; mt < 2; ++mt) {
          acc[mt][ct] = __builtin_amdgcn_mfma_f32_16x16x32_bf16(fah[mt], bh, acc[mt][ct], 0, 0, 0);
          acc[mt][ct] = __builtin_amdgcn_mfma_f32_16x16x32_bf16(fah[mt], bl, acc[mt][ct], 0, 0, 0);
          acc[mt][ct] = __builtin_amdgcn_mfma_f32_16x16x32_bf16(fal[mt], bh, acc[mt][ct], 0, 0, 0);
          acc[mt][ct] = __builtin_amdgcn_mfma_f32_16x16x32_bf16(fal[mt], bl, acc[mt][ct], 0, 0, 0);
        }
      }
    }
    if (k < NK - 1) {
      // frags for k+1 from regs loaded last iteration
      cvt_frag(ar[(k + 1) & 1][0], ar[(k + 1) & 1][1], fah[0], fal[0]);
      cvt_frag(ar[(k + 1) & 1][2], ar[(k + 1) & 1][3], fah[1], fal[1]);
      __syncthreads();  // all waves done reading buf[k&1]; B(k+1) drained
      if (k < NK - 2) {
        const int kb2 = (k + 2) * 32;
        unsigned char* Bt = smem + (k & 1) * 16384;
#pragma unroll
        for (int i = 0; i < 4; ++i) load_lds_16(gB[i] + kb2, Bt + ldsOffB[i]);
      }
    }
  }

  // ---- epilogue: bias+relu -> layer-2 partials -> shuffle reduction ----
  // C layout: col = ct*16 + ln, row = w*32 + mt*16 + quad*4 + reg
  float p[8][2];
#pragma unroll
  for (int s = 0; s < 8; ++s) { p[s][0] = 0.0f; p[s][1] = 0.0f; }
#pragma unroll
  for (int ct = 0; ct < 8; ++ct) {
    const int col = ct * 16 + ln;
    const float bb = b1[col];
    const float w20 = W2[col * 2 + 0];
    const float w21 = W2[col * 2 + 1];
#pragma unroll
    for (int mt = 0; mt < 2; ++mt)
#pragma unroll
      for (int reg = 0; reg < 4; ++reg) {
        float h = acc[mt][ct][reg] + bb;
        h = h > 0.0f ? h : 0.0f;
        p[mt * 4 + reg][0] = fmaf(h, w20, p[mt * 4 + reg][0]);
        p[mt * 4 + reg][1] = fmaf(h, w21, p[mt * 4 + reg][1]);
      }
  }
#pragma unroll
  for (int s = 0; s < 8; ++s)
#pragma unroll
    for (int a = 0; a < 2; ++a) {
      float v = p[s][a];
      v += __shfl_xor(v, 1);
      v += __shfl_xor(v, 2);
      v += __shfl_xor(v, 4);
      v += __shfl_xor(v, 8);
      p[s][a] = v;
    }

  if (ln < 8) {
    float l0 = 0.0f, l1 = 0.0f;
#pragma unroll
    for (int s = 0; s < 8; ++s)
      if (ln == s) { l0 = p[s][0]; l1 = p[s][1]; }
    l0 += b2[0];
    l1 += b2[1];
    const int row = row0 + w * 32 + (ln >> 2) * 16 + quad * 4 + (ln & 3);
    float m = fmaxf(l0, l1);
    float s0 = l0 - m, s1 = l1 - m;
    float e0 = (float)exp((double)s0);
    float e1 = (float)exp((double)s1);
    float lse = (float)log((double)(e0 + e1));
    float lp0 = s0 - lse, lp1 = s1 - lse;
    uint32_t a0, a1, g0b, g1b;
    tf2x32(fk0, fk1, 0u, (uint32_t)(2 * row), &a0, &a1);
    tf2x32(fk0, fk1, 0u, (uint32_t)(2 * row + 1), &g0b, &g1b);
    float g0 = gumbel_from_bits(a0 ^ a1);
    float g1 = gumbel_from_bits(g0b ^ g1b);
    out[row] = ((lp1 + g1) > (lp0 + g0)) ? 1 : 0;
  }
}

extern "C" void kernel_launch(void* const* d_in, const int* in_sizes, int n_in,
                              void* d_out, int out_size, void* d_ws,
                              size_t ws_size, hipStream_t stream) {
  (void)in_sizes; (void)n_in; (void)ws_size; (void)out_size;
  const float* x = (const float*)d_in[0];
  const float* W1 = (const float*)d_in[1];
  const float* b1 = (const float*)d_in[2];
  const float* W2 = (const float*)d_in[3];
  const float* b2 = (const float*)d_in[4];
  int* out = (int*)d_out;

  unsigned short* Bh = (unsigned short*)d_ws;
  unsigned short* Bl = Bh + (size_t)RED_CHS * IN_CHS;

  uint32_t fk0, fk1;
  tf2x32(0u, 0u, 0u, 12345u, &fk0, &fk1);

  w1_convert<<<dim3(32), 256, 0, stream>>>(W1, Bh, Bl);
  rl_head<<<dim3(BATCH / ROWS), 256, 0, stream>>>(x, Bh, Bl, b1, W2, b2, out,
                                                  fk0, fk1);
}